// Round 8
// baseline (1457.913 us; speedup 1.0000x reference)
//
#include <hip/hip_runtime.h>
#include <cstdint>
#include <cmath>

// Problem constants: B=2, F=5, C=256, H=64, W=64, HN=8, hd=16
// Token layout: n = (b*5+f)*4096 + h*64 + w, N = 40960 tokens, channels-last.

typedef __bf16 bf16x8 __attribute__((ext_vector_type(8)));
typedef float f32x4 __attribute__((ext_vector_type(4)));

__device__ __forceinline__ unsigned short f2bf(float f) {
    union { float f; unsigned int u; } v; v.f = f;
    unsigned int r = (v.u + 0x7fffu + ((v.u >> 16) & 1u)) >> 16;
    return (unsigned short)r;
}
__device__ __forceinline__ float bf2f(unsigned short h) {
    union { unsigned int u; float f; } v; v.u = ((unsigned int)h) << 16;
    return v.f;
}
// tanh-form GELU, fully inline
__device__ __forceinline__ float gelu_fast(float x) {
    float z2 = 2.8853900817779268f * x * (0.7978845608028654f + 0.0356774081363001f * x * x);
    float u = __builtin_amdgcn_exp2f(z2);
    return x - x * __builtin_amdgcn_rcpf(1.0f + u);
}

// async global->LDS, 16B per lane; LDS dest = wave-uniform base + lane*16
__device__ __forceinline__ void gld16(const unsigned short* g, unsigned short* l) {
    __builtin_amdgcn_global_load_lds(
        (const __attribute__((address_space(1))) void*)g,
        (__attribute__((address_space(3))) void*)l, 16, 0, 0);
}

// ---------------- fused weight fp32 -> bf16 (all 5 weights, one launch) ----------------
__global__ __launch_bounds__(256) void cvt_all_kernel(
        const float* __restrict__ wh, const float* __restrict__ wv,
        const float* __restrict__ wf, const float* __restrict__ w1,
        const float* __restrict__ w2,
        unsigned short* __restrict__ whb, unsigned short* __restrict__ wvb,
        unsigned short* __restrict__ wfb, unsigned short* __restrict__ w1b,
        unsigned short* __restrict__ w2b) {
    int i = blockIdx.x * 256 + threadIdx.x;   // grid covers 688128 exactly
    const float* s; unsigned short* d; int j;
    if (i < 49152)       { s = wh; d = whb; j = i; }
    else if (i < 98304)  { s = wv; d = wvb; j = i - 49152; }
    else if (i < 163840) { s = wf; d = wfb; j = i - 98304; }
    else if (i < 425984) { s = w1; d = w1b; j = i - 163840; }
    else                 { s = w2; d = w2b; j = i - 425984; }
    d[j] = f2bf(s[j]);
}

// ---------------- fused LN1 + QKV(h&v): one block per (bf, h) line (64 tokens) ----------------
__global__ __launch_bounds__(256) void ln1qkv_kernel(
        const float* __restrict__ x,
        const float* __restrict__ g, const float* __restrict__ bta,
        const unsigned short* __restrict__ whb, const float* __restrict__ bh,
        const unsigned short* __restrict__ wvb, const float* __restrict__ bv,
        unsigned short* __restrict__ xt,
        unsigned short* __restrict__ qkvh, unsigned short* __restrict__ qkvv) {
    __shared__ __align__(16) unsigned short At[64 * 264];   // 33792 B, [token][ch] padded
    __shared__ __align__(16) unsigned short Bs[128 * 64];   // 16384 B, one BK=64 B-tile
    __shared__ float psum[4][64], psq[4][64], meanL[64], rstdL[64];
    __shared__ float gg[256], bb[256];

    int bx = blockIdx.x;
    int bf = bx >> 6, h = bx & 63;
    size_t base = (size_t)bf * 1048576 + (size_t)h * 64;
    int tid = threadIdx.x;
    int w = tid & 63, cg = tid >> 6;
    float s = 0.f, sq = 0.f;
    for (int k = 0; k < 64; ++k) {
        int c = cg * 64 + k;
        float v = x[base + (size_t)c * 4096 + w];
        s += v; sq += v * v;
        At[w * 264 + c] = f2bf(v);
    }
    psum[cg][w] = s; psq[cg][w] = sq;
    gg[tid] = g[tid]; bb[tid] = bta[tid];
    __syncthreads();
    if (tid < 64) {
        float ss = psum[0][tid] + psum[1][tid] + psum[2][tid] + psum[3][tid];
        float qq = psq[0][tid] + psq[1][tid] + psq[2][tid] + psq[3][tid];
        float mean = ss * (1.f / 256.f);
        float var = qq * (1.f / 256.f) - mean * mean;
        meanL[tid] = mean;
        rstdL[tid] = rsqrtf(var + 1e-5f);
    }
    __syncthreads();
    int n0g = bf * 4096 + h * 64;
    for (int t = 0; t < 8; ++t) {
        int idx = t * 256 + tid;
        int tok = idx >> 5, cc = idx & 31;
        unsigned short raw[8];
        *(uint4*)raw = *(const uint4*)&At[tok * 264 + cc * 8];
        *(uint4*)&xt[(size_t)(n0g + tok) * 256 + cc * 8] = *(const uint4*)raw;
        float mean = meanL[tok], rstd = rstdL[tok];
        unsigned short nm[8];
        #pragma unroll
        for (int e = 0; e < 8; ++e) {
            int ch = cc * 8 + e;
            nm[e] = f2bf((bf2f(raw[e]) - mean) * rstd * gg[ch] + bb[ch]);
        }
        *(uint4*)&At[tok * 264 + cc * 8] = *(const uint4*)nm;
    }
    __syncthreads();

    int lane = tid & 63, wvid = tid >> 6;
    int r16 = lane & 15, kg = lane >> 4;
    int srow = wvid * 8 + (lane >> 3);
    int segg = (lane & 7) ^ (lane >> 3);
    unsigned short* lB = Bs + wvid * 512;
    for (int t = 0; t < 6; ++t) {
        const unsigned short* Wt; const float* bias; unsigned short* dst; int ot, aoff;
        if (t < 3) { Wt = whb + t * 16384;       bias = bh + t * 128;       dst = qkvh; ot = t * 128;       aoff = 0; }
        else       { Wt = wvb + (t - 3) * 16384; bias = bv + (t - 3) * 128; dst = qkvv; ot = (t - 3) * 128; aoff = 128; }
        f32x4 acc[4][2] = {};
        for (int kk = 0; kk < 2; ++kk) {
            const unsigned short* pB = Wt + (size_t)srow * 128 + kk * 64 + segg * 8;
            #pragma unroll
            for (int i = 0; i < 4; ++i)
                gld16(pB + (size_t)i * 32 * 128, lB + i * 2048);
            __syncthreads();
            #pragma unroll
            for (int tt = 0; tt < 2; ++tt) {
                int ka = aoff + kk * 64 + (tt * 4 + kg) * 8;
                int ss = ((tt * 4 + kg) ^ (r16 & 7)) * 8;
                bf16x8 af[4], bfr[2];
                #pragma unroll
                for (int i = 0; i < 4; ++i)
                    af[i] = *(const bf16x8*)&At[(i * 16 + r16) * 264 + ka];
                #pragma unroll
                for (int j = 0; j < 2; ++j)
                    bfr[j] = *(const bf16x8*)&Bs[(wvid * 32 + j * 16 + r16) * 64 + ss];
                #pragma unroll
                for (int i = 0; i < 4; ++i)
                    #pragma unroll
                    for (int j = 0; j < 2; ++j)
                        acc[i][j] = __builtin_amdgcn_mfma_f32_16x16x32_bf16(af[i], bfr[j], acc[i][j], 0, 0, 0);
            }
            __syncthreads();
        }
        float biasv[2];
        #pragma unroll
        for (int j = 0; j < 2; ++j) biasv[j] = bias[wvid * 32 + j * 16 + r16];
        #pragma unroll
        for (int i = 0; i < 4; ++i)
            #pragma unroll
            for (int j = 0; j < 2; ++j)
                #pragma unroll
                for (int r = 0; r < 4; ++r) {
                    int m = i * 16 + kg * 4 + r;
                    int nc = ot + wvid * 32 + j * 16 + r16;
                    dst[(size_t)(n0g + m) * 384 + nc] = f2bf(acc[i][j][r] + biasv[j]);
                }
    }
}

// ---------------- 128x256 MFMA GEMM: C(Mx256n) = A(MxK) * B(NxK)^T (+epilogue) ----------------
// BK=64, 4 waves as 2x2, wave-tile 64x128 (4x8 of 16x16x32). global_load_lds staging.
// modes: 2 = bias + fast GELU, store bf16                       (FFN1)
//        3 = bias + res(bf16,256), fp32 transposed store        (FFN2 -> out)
//        4 = bias + res(bf16,256) -> yb; then LN2 -> C2 (tn)    (proj + LN2)
__global__ __launch_bounds__(256, 2) void gemm256_kernel(
        const unsigned short* __restrict__ A, int lda,
        const unsigned short* __restrict__ B,
        const float* __restrict__ bias,
        unsigned short* __restrict__ C, int ldc,
        const unsigned short* __restrict__ res,
        float* __restrict__ outT,
        int K, int mode,
        const float* __restrict__ g2, const float* __restrict__ b2,
        unsigned short* __restrict__ C2) {
    __shared__ __align__(16) unsigned char smem[49152];   // As 16KB | Bs 32KB
    unsigned short* As = (unsigned short*)smem;
    unsigned short* Bs = (unsigned short*)(smem + 16384);

    int tid = threadIdx.x;
    int lane = tid & 63, wvid = tid >> 6;
    int wm = wvid >> 1, wn = wvid & 1;          // wave tile: rows wm*64..+64, cols wn*128..+128
    int r16 = lane & 15, kg = lane >> 4;

    // XCD-aware remap
    int nx = gridDim.x;
    int L = blockIdx.y * nx + blockIdx.x;
    int T = nx * gridDim.y;
    int newL = (T & 7) ? L : ((L & 7) * (T >> 3) + (L >> 3));
    int nt = newL % nx, mt = newL / nx;
    int m0 = mt * 128, n0 = nt * 256;

    int srow = wvid * 8 + (lane >> 3);
    int segg = (lane & 7) ^ (lane >> 3);
    const unsigned short* pA = A + (size_t)(m0 + srow) * lda + segg * 8;
    const unsigned short* pB = B + (size_t)(n0 + srow) * K + segg * 8;
    unsigned short* lA = As + wvid * 512;
    unsigned short* lB = Bs + wvid * 512;

    f32x4 acc[4][8] = {};
    for (int k0 = 0; k0 < K; k0 += 64) {
        #pragma unroll
        for (int i = 0; i < 4; ++i)
            gld16(pA + (size_t)i * 32 * lda, lA + i * 2048);
        #pragma unroll
        for (int i = 0; i < 8; ++i)
            gld16(pB + (size_t)i * 32 * K, lB + i * 2048);
        pA += 64; pB += 64;
        __syncthreads();
        #pragma unroll
        for (int t = 0; t < 2; ++t) {
            bf16x8 af[4], bfr[8];
            int ss = ((t * 4 + kg) ^ (r16 & 7)) * 8;
            #pragma unroll
            for (int i = 0; i < 4; ++i)
                af[i] = *(const bf16x8*)&As[(wm * 64 + i * 16 + r16) * 64 + ss];
            #pragma unroll
            for (int j = 0; j < 8; ++j)
                bfr[j] = *(const bf16x8*)&Bs[(wn * 128 + j * 16 + r16) * 64 + ss];
            #pragma unroll
            for (int i = 0; i < 4; ++i)
                #pragma unroll
                for (int j = 0; j < 8; ++j)
                    acc[i][j] = __builtin_amdgcn_mfma_f32_16x16x32_bf16(af[i], bfr[j], acc[i][j], 0, 0, 0);
        }
        __syncthreads();
    }

    if (mode == 2) {
        float biasv[8];
        #pragma unroll
        for (int j = 0; j < 8; ++j) biasv[j] = bias[n0 + wn * 128 + j * 16 + r16];
        #pragma unroll
        for (int i = 0; i < 4; ++i)
            #pragma unroll
            for (int j = 0; j < 8; ++j)
                #pragma unroll
                for (int r = 0; r < 4; ++r) {
                    int m = m0 + wm * 64 + i * 16 + kg * 4 + r;
                    int n = n0 + wn * 128 + j * 16 + r16;
                    C[(size_t)m * ldc + n] = f2bf(gelu_fast(acc[i][j][r] + biasv[j]));
                }
        return;
    }

    if (mode == 3) {
        float* fl = (float*)smem;               // [128 tokens][64] fp32, XOR col swizzle
        int bfi = m0 >> 12;
        int hbase = (m0 >> 6) & 63;             // block spans h = hbase, hbase+1
        for (int p = 0; p < 4; ++p) {           // channel groups of 64
            __syncthreads();
            if (wn == (p >> 1)) {
                int jb = (p & 1) * 4;
                #pragma unroll
                for (int i = 0; i < 4; ++i)
                    #pragma unroll
                    for (int jj = 0; jj < 4; ++jj)
                        #pragma unroll
                        for (int r = 0; r < 4; ++r) {
                            int ml = wm * 64 + i * 16 + kg * 4 + r;
                            int nl = jj * 16 + r16;
                            int n = p * 64 + nl;
                            float v = acc[i][jb + jj][r] + bias[n] + bf2f(res[(size_t)(m0 + ml) * 256 + n]);
                            fl[ml * 64 + (nl ^ (ml & 63))] = v;
                        }
            }
            __syncthreads();
            for (int r = wvid; r < 128; r += 4) {
                int nl = r & 63, tl2 = r >> 6;
                int token = tl2 * 64 + lane;
                outT[(size_t)bfi * 1048576 + (size_t)(p * 64 + nl) * 4096 +
                     (size_t)(hbase + tl2) * 64 + lane] = fl[token * 64 + (nl ^ (token & 63))];
            }
        }
        return;
    }

    // mode 4: y = acc + bias + res -> C (yb); row LN over 256 cols -> C2 (tn)
    float* ssum = (float*)smem;                 // [128][2]
    float* ssq  = ssum + 256;
    float biasv[8];
    #pragma unroll
    for (int j = 0; j < 8; ++j) biasv[j] = bias[wn * 128 + j * 16 + r16];
    const unsigned short* resp = res + (size_t)(m0 + wm * 64) * 256 + wn * 128;
    #pragma unroll
    for (int i = 0; i < 4; ++i)
        #pragma unroll
        for (int r = 0; r < 4; ++r) {
            int row = i * 16 + kg * 4 + r;
            #pragma unroll
            for (int j = 0; j < 8; ++j) {
                float v = acc[i][j][r] + biasv[j] + bf2f(resp[(size_t)row * 256 + j * 16 + r16]);
                acc[i][j][r] = v;
                C[(size_t)(m0 + wm * 64 + row) * 256 + wn * 128 + j * 16 + r16] = f2bf(v);
            }
        }
    #pragma unroll
    for (int i = 0; i < 4; ++i)
        #pragma unroll
        for (int r = 0; r < 4; ++r) {
            float s = 0.f, sq = 0.f;
            #pragma unroll
            for (int j = 0; j < 8; ++j) { float v = acc[i][j][r]; s += v; sq += v * v; }
            s += __shfl_xor(s, 1); sq += __shfl_xor(sq, 1);
            s += __shfl_xor(s, 2); sq += __shfl_xor(sq, 2);
            s += __shfl_xor(s, 4); sq += __shfl_xor(sq, 4);
            s += __shfl_xor(s, 8); sq += __shfl_xor(sq, 8);
            if (r16 == 0) {
                int mr = wm * 64 + i * 16 + kg * 4 + r;
                ssum[mr * 2 + wn] = s;
                ssq[mr * 2 + wn] = sq;
            }
        }
    __syncthreads();
    float g2v[8], b2v[8];
    #pragma unroll
    for (int j = 0; j < 8; ++j) {
        g2v[j] = g2[wn * 128 + j * 16 + r16];
        b2v[j] = b2[wn * 128 + j * 16 + r16];
    }
    #pragma unroll
    for (int i = 0; i < 4; ++i)
        #pragma unroll
        for (int r = 0; r < 4; ++r) {
            int mr = wm * 64 + i * 16 + kg * 4 + r;
            float sum = ssum[mr * 2] + ssum[mr * 2 + 1];
            float sq  = ssq[mr * 2] + ssq[mr * 2 + 1];
            float mean = sum * (1.f / 256.f);
            float var = sq * (1.f / 256.f) - mean * mean;
            float rstd = rsqrtf(var + 1e-5f);
            #pragma unroll
            for (int j = 0; j < 8; ++j) {
                float tv = (acc[i][j][r] - mean) * rstd * g2v[j] + b2v[j];
                C2[(size_t)(m0 + mr) * 256 + wn * 128 + j * 16 + r16] = f2bf(tv);
            }
        }
}

// ---------------- attention (both directions, one launch): per (dir, b, head, line) ----------------
__global__ __launch_bounds__(256) void attn_kernel(const unsigned short* __restrict__ qkvH,
                                                   const unsigned short* __restrict__ qkvV,
                                                   unsigned short* __restrict__ ao) {
    __shared__ unsigned short qL[5 * 1024], kL[5 * 1024], vL[5 * 1024];
    __shared__ float sL[25];
    int g = blockIdx.x;
    int vertical = g >> 10;
    const unsigned short* qkv = vertical ? qkvV : qkvH;
    int lw = g & 63;
    int head = (g >> 6) & 7;
    int b = (g >> 9) & 1;
    int tid = threadIdx.x;
    for (int c = tid; c < 640; c += 256) {
        int f = c >> 7, rem = c & 127;
        int pos = rem >> 1, d0 = (rem & 1) * 8;
        size_t n = (size_t)b * 20480 + (size_t)f * 4096 +
                   (vertical ? (pos * 64 + lw) : (lw * 64 + pos));
        size_t src = n * 384 + head * 16 + d0;
        *(uint4*)&qL[c * 8] = *(const uint4*)&qkv[src];
        *(uint4*)&kL[c * 8] = *(const uint4*)&qkv[src + 128];
        *(uint4*)&vL[c * 8] = *(const uint4*)&qkv[src + 256];
    }
    __syncthreads();
    int lane = tid & 63, wwv = tid >> 6;
    for (int p = wwv; p < 25; p += 4) {
        int qf = p / 5, kf = p - qf * 5;
        float acc = 0.f;
        const unsigned short* qp = &qL[qf * 1024 + lane * 16];
        const unsigned short* kp = &kL[kf * 1024 + lane * 16];
        #pragma unroll
        for (int t = 0; t < 16; ++t) acc += bf2f(qp[t]) * bf2f(kp[t]);
        for (int off = 32; off; off >>= 1) acc += __shfl_down(acc, off);
        if (lane == 0) sL[p] = acc * 0.03125f;   // 1/sqrt(1024)
    }
    __syncthreads();
    if (tid < 5) {
        float mx = -1e30f;
        for (int kf = 0; kf < 5; ++kf) mx = fmaxf(mx, sL[tid * 5 + kf]);
        float e[5], sum = 0.f;
        for (int kf = 0; kf < 5; ++kf) { e[kf] = expf(sL[tid * 5 + kf] - mx); sum += e[kf]; }
        float inv = 1.f / sum;
        for (int kf = 0; kf < 5; ++kf) sL[tid * 5 + kf] = e[kf] * inv;
    }
    __syncthreads();
    int coff = vertical ? 128 : 0;
    for (int c = tid; c < 640; c += 256) {
        int qf = c >> 7, rem = c & 127;
        int pos = rem >> 1, d0 = (rem & 1) * 8;
        float accv[8] = {};
        #pragma unroll
        for (int kf = 0; kf < 5; ++kf) {
            float w = sL[qf * 5 + kf];
            const unsigned short* vp = &vL[kf * 1024 + rem * 8];
            #pragma unroll
            for (int e = 0; e < 8; ++e) accv[e] += w * bf2f(vp[e]);
        }
        unsigned short pk[8];
        #pragma unroll
        for (int e = 0; e < 8; ++e) pk[e] = f2bf(accv[e]);
        size_t n = (size_t)b * 20480 + (size_t)qf * 4096 +
                   (vertical ? (pos * 64 + lw) : (lw * 64 + pos));
        *(uint4*)&ao[n * 256 + coff + head * 16 + d0] = *(const uint4*)pk;
    }
}

extern "C" void kernel_launch(void* const* d_in, const int* in_sizes, int n_in,
                              void* d_out, int out_size, void* d_ws, size_t ws_size,
                              hipStream_t stream) {
    (void)in_sizes; (void)n_in; (void)out_size; (void)ws_size;
    const float* x    = (const float*)d_in[0];
    const float* ln1g = (const float*)d_in[1];
    const float* ln1b = (const float*)d_in[2];
    const float* wh   = (const float*)d_in[3];
    const float* bh   = (const float*)d_in[4];
    const float* wv   = (const float*)d_in[5];
    const float* bv   = (const float*)d_in[6];
    const float* wf   = (const float*)d_in[7];
    const float* bfp  = (const float*)d_in[8];
    const float* ln2g = (const float*)d_in[9];
    const float* ln2b = (const float*)d_in[10];
    const float* w1   = (const float*)d_in[11];
    const float* b1   = (const float*)d_in[12];
    const float* w2   = (const float*)d_in[13];
    const float* b2   = (const float*)d_in[14];
    float* out = (float*)d_out;
    char* ws = (char*)d_ws;

    // workspace layout (total ~148.4 MB)
    unsigned short* whb = (unsigned short*)(ws + 0);
    unsigned short* wvb = (unsigned short*)(ws + 98304);
    unsigned short* wfb = (unsigned short*)(ws + 196608);
    unsigned short* w1b = (unsigned short*)(ws + 327680);
    unsigned short* w2b = (unsigned short*)(ws + 851968);
    const size_t off = 1572864;
    unsigned short* tnb  = (unsigned short*)(ws + off);                    // 21.0 MB
    unsigned short* xt   = (unsigned short*)(ws + off + 20971520ull);      // 21.0 MB
    unsigned short* qkvh = (unsigned short*)(ws + off + 41943040ull);      // 31.5 MB (hid part 1)
    unsigned short* qkvv = (unsigned short*)(ws + off + 73400320ull);      // 31.5 MB (hid part 2)
    unsigned short* ao   = (unsigned short*)(ws + off + 104857600ull);     // 21.0 MB (hid part 3)
    unsigned short* yb   = (unsigned short*)(ws + off + 125829120ull);     // 21.0 MB
    unsigned short* hid  = qkvh;   // hid (N x 1024, 84 MB) overlays qkvh/qkvv/ao (dead by FFN1)

    cvt_all_kernel<<<2688, 256, 0, stream>>>(wh, wv, wf, w1, w2, whb, wvb, wfb, w1b, w2b);

    // fused LN1 + QKV (both halves): writes xt, qkvh, qkvv
    ln1qkv_kernel<<<640, 256, 0, stream>>>(x, ln1g, ln1b, whb, bh, wvb, bv, xt, qkvh, qkvv);

    attn_kernel<<<2048, 256, 0, stream>>>(qkvh, qkvv, ao);

    // proj + residual + LN2 (fused): yb = ao@wf^T + bf + x ; tnb = LN2(yb)
    gemm256_kernel<<<dim3(1, 320), 256, 0, stream>>>(ao, 256, wfb, bfp, yb, 256, xt, nullptr,
                                                     256, 4, ln2g, ln2b, tnb);

    // FFN1: hid = gelu(tn @ w1^T + b1)
    gemm256_kernel<<<dim3(4, 320), 256, 0, stream>>>(tnb, 256, w1b, b1, hid, 1024, nullptr, nullptr,
                                                     256, 2, nullptr, nullptr, nullptr);
    // FFN2 + residual + transpose: out = (y + hid @ w2^T + b2) -> (B,F,C,H,W) fp32
    gemm256_kernel<<<dim3(1, 320), 256, 0, stream>>>(hid, 1024, w2b, b2, nullptr, 256, yb, out,
                                                     1024, 3, nullptr, nullptr, nullptr);
}

// Round 9
// 318.345 us; speedup vs baseline: 4.5797x; 4.5797x over previous
//
#include <hip/hip_runtime.h>
#include <cstdint>
#include <cmath>

// Problem constants: B=2, F=5, C=256, H=64, W=64, HN=8, hd=16
// Token layout: n = (b*5+f)*4096 + h*64 + w, N = 40960 tokens, channels-last.

typedef __bf16 bf16x8 __attribute__((ext_vector_type(8)));
typedef float f32x4 __attribute__((ext_vector_type(4)));

__device__ __forceinline__ unsigned short f2bf(float f) {
    union { float f; unsigned int u; } v; v.f = f;
    unsigned int r = (v.u + 0x7fffu + ((v.u >> 16) & 1u)) >> 16;
    return (unsigned short)r;
}
__device__ __forceinline__ float bf2f(unsigned short h) {
    union { unsigned int u; float f; } v; v.u = ((unsigned int)h) << 16;
    return v.f;
}
// tanh-form GELU, fully inline
__device__ __forceinline__ float gelu_fast(float x) {
    float z2 = 2.8853900817779268f * x * (0.7978845608028654f + 0.0356774081363001f * x * x);
    float u = __builtin_amdgcn_exp2f(z2);
    return x - x * __builtin_amdgcn_rcpf(1.0f + u);
}

// async global->LDS, 16B per lane; LDS dest = wave-uniform base + lane*16
__device__ __forceinline__ void gld16(const unsigned short* g, unsigned short* l) {
    __builtin_amdgcn_global_load_lds(
        (const __attribute__((address_space(1))) void*)g,
        (__attribute__((address_space(3))) void*)l, 16, 0, 0);
}

// ---------------- fused weight fp32 -> bf16 (all 5 weights, one launch) ----------------
__global__ __launch_bounds__(256) void cvt_all_kernel(
        const float* __restrict__ wh, const float* __restrict__ wv,
        const float* __restrict__ wf, const float* __restrict__ w1,
        const float* __restrict__ w2,
        unsigned short* __restrict__ whb, unsigned short* __restrict__ wvb,
        unsigned short* __restrict__ wfb, unsigned short* __restrict__ w1b,
        unsigned short* __restrict__ w2b) {
    int i = blockIdx.x * 256 + threadIdx.x;   // grid covers 688128 exactly
    const float* s; unsigned short* d; int j;
    if (i < 49152)       { s = wh; d = whb; j = i; }
    else if (i < 98304)  { s = wv; d = wvb; j = i - 49152; }
    else if (i < 163840) { s = wf; d = wfb; j = i - 98304; }
    else if (i < 425984) { s = w1; d = w1b; j = i - 163840; }
    else                 { s = w2; d = w2b; j = i - 425984; }
    d[j] = f2bf(s[j]);
}

// ---------------- fused LN1 + QKV(h&v): one block per (bf, h) line (64 tokens) ----------------
__global__ __launch_bounds__(256) void ln1qkv_kernel(
        const float* __restrict__ x,
        const float* __restrict__ g, const float* __restrict__ bta,
        const unsigned short* __restrict__ whb, const float* __restrict__ bh,
        const unsigned short* __restrict__ wvb, const float* __restrict__ bv,
        unsigned short* __restrict__ xt,
        unsigned short* __restrict__ qkvh, unsigned short* __restrict__ qkvv) {
    __shared__ __align__(16) unsigned short At[64 * 264];   // 33792 B, [token][ch] padded
    __shared__ __align__(16) unsigned short Bs[128 * 64];   // 16384 B, one BK=64 B-tile
    __shared__ float psum[4][64], psq[4][64], meanL[64], rstdL[64];
    __shared__ float gg[256], bb[256];

    int bx = blockIdx.x;
    int bf = bx >> 6, h = bx & 63;
    size_t base = (size_t)bf * 1048576 + (size_t)h * 64;
    int tid = threadIdx.x;
    int w = tid & 63, cg = tid >> 6;
    float s = 0.f, sq = 0.f;
    for (int k = 0; k < 64; ++k) {
        int c = cg * 64 + k;
        float v = x[base + (size_t)c * 4096 + w];
        s += v; sq += v * v;
        At[w * 264 + c] = f2bf(v);
    }
    psum[cg][w] = s; psq[cg][w] = sq;
    gg[tid] = g[tid]; bb[tid] = bta[tid];
    __syncthreads();
    if (tid < 64) {
        float ss = psum[0][tid] + psum[1][tid] + psum[2][tid] + psum[3][tid];
        float qq = psq[0][tid] + psq[1][tid] + psq[2][tid] + psq[3][tid];
        float mean = ss * (1.f / 256.f);
        float var = qq * (1.f / 256.f) - mean * mean;
        meanL[tid] = mean;
        rstdL[tid] = rsqrtf(var + 1e-5f);
    }
    __syncthreads();
    int n0g = bf * 4096 + h * 64;
    for (int t = 0; t < 8; ++t) {
        int idx = t * 256 + tid;
        int tok = idx >> 5, cc = idx & 31;
        unsigned short raw[8];
        *(uint4*)raw = *(const uint4*)&At[tok * 264 + cc * 8];
        *(uint4*)&xt[(size_t)(n0g + tok) * 256 + cc * 8] = *(const uint4*)raw;
        float mean = meanL[tok], rstd = rstdL[tok];
        unsigned short nm[8];
        #pragma unroll
        for (int e = 0; e < 8; ++e) {
            int ch = cc * 8 + e;
            nm[e] = f2bf((bf2f(raw[e]) - mean) * rstd * gg[ch] + bb[ch]);
        }
        *(uint4*)&At[tok * 264 + cc * 8] = *(const uint4*)nm;
    }
    __syncthreads();

    int lane = tid & 63, wvid = tid >> 6;
    int r16 = lane & 15, kg = lane >> 4;
    int srow = wvid * 8 + (lane >> 3);
    int segg = (lane & 7) ^ (lane >> 3);
    unsigned short* lB = Bs + wvid * 512;
    for (int t = 0; t < 6; ++t) {
        const unsigned short* Wt; const float* bias; unsigned short* dst; int ot, aoff;
        if (t < 3) { Wt = whb + t * 16384;       bias = bh + t * 128;       dst = qkvh; ot = t * 128;       aoff = 0; }
        else       { Wt = wvb + (t - 3) * 16384; bias = bv + (t - 3) * 128; dst = qkvv; ot = (t - 3) * 128; aoff = 128; }
        f32x4 acc[4][2] = {};
        for (int kk = 0; kk < 2; ++kk) {
            const unsigned short* pB = Wt + (size_t)srow * 128 + kk * 64 + segg * 8;
            #pragma unroll
            for (int i = 0; i < 4; ++i)
                gld16(pB + (size_t)i * 32 * 128, lB + i * 2048);
            __syncthreads();
            #pragma unroll
            for (int tt = 0; tt < 2; ++tt) {
                int ka = aoff + kk * 64 + (tt * 4 + kg) * 8;
                int ss = ((tt * 4 + kg) ^ (r16 & 7)) * 8;
                bf16x8 af[4], bfr[2];
                #pragma unroll
                for (int i = 0; i < 4; ++i)
                    af[i] = *(const bf16x8*)&At[(i * 16 + r16) * 264 + ka];
                #pragma unroll
                for (int j = 0; j < 2; ++j)
                    bfr[j] = *(const bf16x8*)&Bs[(wvid * 32 + j * 16 + r16) * 64 + ss];
                #pragma unroll
                for (int i = 0; i < 4; ++i)
                    #pragma unroll
                    for (int j = 0; j < 2; ++j)
                        acc[i][j] = __builtin_amdgcn_mfma_f32_16x16x32_bf16(af[i], bfr[j], acc[i][j], 0, 0, 0);
            }
            __syncthreads();
        }
        float biasv[2];
        #pragma unroll
        for (int j = 0; j < 2; ++j) biasv[j] = bias[wvid * 32 + j * 16 + r16];
        #pragma unroll
        for (int i = 0; i < 4; ++i)
            #pragma unroll
            for (int j = 0; j < 2; ++j)
                #pragma unroll
                for (int r = 0; r < 4; ++r) {
                    int m = i * 16 + kg * 4 + r;
                    int nc = ot + wvid * 32 + j * 16 + r16;
                    dst[(size_t)(n0g + m) * 384 + nc] = f2bf(acc[i][j][r] + biasv[j]);
                }
    }
}

// ---------------- 128x256 MFMA GEMM: C(Mx256n) = A(MxK) * B(NxK)^T (+epilogue) ----------------
// BK=64, 4 waves as 2x2, wave-tile 64x128 (4x8 of 16x16x32). global_load_lds staging.
// NOTE: every acc[] subscript must be compile-time constant (dynamic indexing
// spills the whole accumulator array to scratch -- R8 postmortem: 1.36 GB scratch traffic).
// modes: 2 = bias + fast GELU, store bf16                       (FFN1)
//        3 = bias + res(bf16,256), fp32 transposed store        (FFN2 -> out)
//        4 = bias + res(bf16,256) -> yb; then LN2 -> C2 (tn)    (proj + LN2)
__global__ __launch_bounds__(256, 2) void gemm256_kernel(
        const unsigned short* __restrict__ A, int lda,
        const unsigned short* __restrict__ B,
        const float* __restrict__ bias,
        unsigned short* __restrict__ C, int ldc,
        const unsigned short* __restrict__ res,
        float* __restrict__ outT,
        int K, int mode,
        const float* __restrict__ g2, const float* __restrict__ b2,
        unsigned short* __restrict__ C2) {
    __shared__ __align__(16) unsigned char smem[49152];   // As 16KB | Bs 32KB
    unsigned short* As = (unsigned short*)smem;
    unsigned short* Bs = (unsigned short*)(smem + 16384);

    int tid = threadIdx.x;
    int lane = tid & 63, wvid = tid >> 6;
    int wm = wvid >> 1, wn = wvid & 1;          // wave tile: rows wm*64..+64, cols wn*128..+128
    int r16 = lane & 15, kg = lane >> 4;

    // XCD-aware remap
    int nx = gridDim.x;
    int L = blockIdx.y * nx + blockIdx.x;
    int T = nx * gridDim.y;
    int newL = (T & 7) ? L : ((L & 7) * (T >> 3) + (L >> 3));
    int nt = newL % nx, mt = newL / nx;
    int m0 = mt * 128, n0 = nt * 256;

    int srow = wvid * 8 + (lane >> 3);
    int segg = (lane & 7) ^ (lane >> 3);
    const unsigned short* pA = A + (size_t)(m0 + srow) * lda + segg * 8;
    const unsigned short* pB = B + (size_t)(n0 + srow) * K + segg * 8;
    unsigned short* lA = As + wvid * 512;
    unsigned short* lB = Bs + wvid * 512;

    f32x4 acc[4][8] = {};
    for (int k0 = 0; k0 < K; k0 += 64) {
        #pragma unroll
        for (int i = 0; i < 4; ++i)
            gld16(pA + (size_t)i * 32 * lda, lA + i * 2048);
        #pragma unroll
        for (int i = 0; i < 8; ++i)
            gld16(pB + (size_t)i * 32 * K, lB + i * 2048);
        pA += 64; pB += 64;
        __syncthreads();
        #pragma unroll
        for (int t = 0; t < 2; ++t) {
            bf16x8 af[4], bfr[8];
            int ss = ((t * 4 + kg) ^ (r16 & 7)) * 8;
            #pragma unroll
            for (int i = 0; i < 4; ++i)
                af[i] = *(const bf16x8*)&As[(wm * 64 + i * 16 + r16) * 64 + ss];
            #pragma unroll
            for (int j = 0; j < 8; ++j)
                bfr[j] = *(const bf16x8*)&Bs[(wn * 128 + j * 16 + r16) * 64 + ss];
            #pragma unroll
            for (int i = 0; i < 4; ++i)
                #pragma unroll
                for (int j = 0; j < 8; ++j)
                    acc[i][j] = __builtin_amdgcn_mfma_f32_16x16x32_bf16(af[i], bfr[j], acc[i][j], 0, 0, 0);
        }
        __syncthreads();
    }

    if (mode == 2) {
        float biasv[8];
        #pragma unroll
        for (int j = 0; j < 8; ++j) biasv[j] = bias[n0 + wn * 128 + j * 16 + r16];
        #pragma unroll
        for (int i = 0; i < 4; ++i)
            #pragma unroll
            for (int j = 0; j < 8; ++j)
                #pragma unroll
                for (int r = 0; r < 4; ++r) {
                    int m = m0 + wm * 64 + i * 16 + kg * 4 + r;
                    int n = n0 + wn * 128 + j * 16 + r16;
                    C[(size_t)m * ldc + n] = f2bf(gelu_fast(acc[i][j][r] + biasv[j]));
                }
        return;
    }

    if (mode == 3) {
        float* fl = (float*)smem;               // [128 tokens][64] fp32, XOR col swizzle
        int bfi = m0 >> 12;
        int hbase = (m0 >> 6) & 63;             // block spans h = hbase, hbase+1
        #pragma unroll                          // MUST unroll: jb below indexes acc[] (R8 spill bug)
        for (int p = 0; p < 4; ++p) {           // channel groups of 64
            __syncthreads();
            if (wn == (p >> 1)) {
                const int jb = (p & 1) * 4;
                #pragma unroll
                for (int i = 0; i < 4; ++i)
                    #pragma unroll
                    for (int jj = 0; jj < 4; ++jj)
                        #pragma unroll
                        for (int r = 0; r < 4; ++r) {
                            int ml = wm * 64 + i * 16 + kg * 4 + r;
                            int nl = jj * 16 + r16;
                            int n = p * 64 + nl;
                            float v = acc[i][jb + jj][r] + bias[n] + bf2f(res[(size_t)(m0 + ml) * 256 + n]);
                            fl[ml * 64 + (nl ^ (ml & 63))] = v;
                        }
            }
            __syncthreads();
            for (int r = wvid; r < 128; r += 4) {
                int nl = r & 63, tl2 = r >> 6;
                int token = tl2 * 64 + lane;
                outT[(size_t)bfi * 1048576 + (size_t)(p * 64 + nl) * 4096 +
                     (size_t)(hbase + tl2) * 64 + lane] = fl[token * 64 + (nl ^ (token & 63))];
            }
        }
        return;
    }

    // mode 4: y = acc + bias + res -> C (yb); row LN over 256 cols -> C2 (tn)
    float* ssum = (float*)smem;                 // [128][2]
    float* ssq  = ssum + 256;
    float biasv[8];
    #pragma unroll
    for (int j = 0; j < 8; ++j) biasv[j] = bias[wn * 128 + j * 16 + r16];
    const unsigned short* resp = res + (size_t)(m0 + wm * 64) * 256 + wn * 128;
    #pragma unroll
    for (int i = 0; i < 4; ++i)
        #pragma unroll
        for (int r = 0; r < 4; ++r) {
            int row = i * 16 + kg * 4 + r;
            #pragma unroll
            for (int j = 0; j < 8; ++j) {
                float v = acc[i][j][r] + biasv[j] + bf2f(resp[(size_t)row * 256 + j * 16 + r16]);
                acc[i][j][r] = v;
                C[(size_t)(m0 + wm * 64 + row) * 256 + wn * 128 + j * 16 + r16] = f2bf(v);
            }
        }
    #pragma unroll
    for (int i = 0; i < 4; ++i)
        #pragma unroll
        for (int r = 0; r < 4; ++r) {
            float s = 0.f, sq = 0.f;
            #pragma unroll
            for (int j = 0; j < 8; ++j) { float v = acc[i][j][r]; s += v; sq += v * v; }
            s += __shfl_xor(s, 1); sq += __shfl_xor(sq, 1);
            s += __shfl_xor(s, 2); sq += __shfl_xor(sq, 2);
            s += __shfl_xor(s, 4); sq += __shfl_xor(sq, 4);
            s += __shfl_xor(s, 8); sq += __shfl_xor(sq, 8);
            if (r16 == 0) {
                int mr = wm * 64 + i * 16 + kg * 4 + r;
                ssum[mr * 2 + wn] = s;
                ssq[mr * 2 + wn] = sq;
            }
        }
    __syncthreads();
    float g2v[8], b2v[8];
    #pragma unroll
    for (int j = 0; j < 8; ++j) {
        g2v[j] = g2[wn * 128 + j * 16 + r16];
        b2v[j] = b2[wn * 128 + j * 16 + r16];
    }
    #pragma unroll
    for (int i = 0; i < 4; ++i)
        #pragma unroll
        for (int r = 0; r < 4; ++r) {
            int mr = wm * 64 + i * 16 + kg * 4 + r;
            float sum = ssum[mr * 2] + ssum[mr * 2 + 1];
            float sq  = ssq[mr * 2] + ssq[mr * 2 + 1];
            float mean = sum * (1.f / 256.f);
            float var = sq * (1.f / 256.f) - mean * mean;
            float rstd = rsqrtf(var + 1e-5f);
            #pragma unroll
            for (int j = 0; j < 8; ++j) {
                float tv = (acc[i][j][r] - mean) * rstd * g2v[j] + b2v[j];
                C2[(size_t)(m0 + mr) * 256 + wn * 128 + j * 16 + r16] = f2bf(tv);
            }
        }
}

// ---------------- attention (both directions, one launch): per (dir, b, head, line) ----------------
__global__ __launch_bounds__(256) void attn_kernel(const unsigned short* __restrict__ qkvH,
                                                   const unsigned short* __restrict__ qkvV,
                                                   unsigned short* __restrict__ ao) {
    __shared__ unsigned short qL[5 * 1024], kL[5 * 1024], vL[5 * 1024];
    __shared__ float sL[25];
    int g = blockIdx.x;
    int vertical = g >> 10;
    const unsigned short* qkv = vertical ? qkvV : qkvH;
    int lw = g & 63;
    int head = (g >> 6) & 7;
    int b = (g >> 9) & 1;
    int tid = threadIdx.x;
    for (int c = tid; c < 640; c += 256) {
        int f = c >> 7, rem = c & 127;
        int pos = rem >> 1, d0 = (rem & 1) * 8;
        size_t n = (size_t)b * 20480 + (size_t)f * 4096 +
                   (vertical ? (pos * 64 + lw) : (lw * 64 + pos));
        size_t src = n * 384 + head * 16 + d0;
        *(uint4*)&qL[c * 8] = *(const uint4*)&qkv[src];
        *(uint4*)&kL[c * 8] = *(const uint4*)&qkv[src + 128];
        *(uint4*)&vL[c * 8] = *(const uint4*)&qkv[src + 256];
    }
    __syncthreads();
    int lane = tid & 63, wwv = tid >> 6;
    for (int p = wwv; p < 25; p += 4) {
        int qf = p / 5, kf = p - qf * 5;
        float acc = 0.f;
        const unsigned short* qp = &qL[qf * 1024 + lane * 16];
        const unsigned short* kp = &kL[kf * 1024 + lane * 16];
        #pragma unroll
        for (int t = 0; t < 16; ++t) acc += bf2f(qp[t]) * bf2f(kp[t]);
        for (int off = 32; off; off >>= 1) acc += __shfl_down(acc, off);
        if (lane == 0) sL[p] = acc * 0.03125f;   // 1/sqrt(1024)
    }
    __syncthreads();
    if (tid < 5) {
        float mx = -1e30f;
        for (int kf = 0; kf < 5; ++kf) mx = fmaxf(mx, sL[tid * 5 + kf]);
        float e[5], sum = 0.f;
        for (int kf = 0; kf < 5; ++kf) { e[kf] = expf(sL[tid * 5 + kf] - mx); sum += e[kf]; }
        float inv = 1.f / sum;
        for (int kf = 0; kf < 5; ++kf) sL[tid * 5 + kf] = e[kf] * inv;
    }
    __syncthreads();
    int coff = vertical ? 128 : 0;
    for (int c = tid; c < 640; c += 256) {
        int qf = c >> 7, rem = c & 127;
        int pos = rem >> 1, d0 = (rem & 1) * 8;
        float accv[8] = {};
        #pragma unroll
        for (int kf = 0; kf < 5; ++kf) {
            float w = sL[qf * 5 + kf];
            const unsigned short* vp = &vL[kf * 1024 + rem * 8];
            #pragma unroll
            for (int e = 0; e < 8; ++e) accv[e] += w * bf2f(vp[e]);
        }
        unsigned short pk[8];
        #pragma unroll
        for (int e = 0; e < 8; ++e) pk[e] = f2bf(accv[e]);
        size_t n = (size_t)b * 20480 + (size_t)qf * 4096 +
                   (vertical ? (pos * 64 + lw) : (lw * 64 + pos));
        *(uint4*)&ao[n * 256 + coff + head * 16 + d0] = *(const uint4*)pk;
    }
}

extern "C" void kernel_launch(void* const* d_in, const int* in_sizes, int n_in,
                              void* d_out, int out_size, void* d_ws, size_t ws_size,
                              hipStream_t stream) {
    (void)in_sizes; (void)n_in; (void)out_size; (void)ws_size;
    const float* x    = (const float*)d_in[0];
    const float* ln1g = (const float*)d_in[1];
    const float* ln1b = (const float*)d_in[2];
    const float* wh   = (const float*)d_in[3];
    const float* bh   = (const float*)d_in[4];
    const float* wv   = (const float*)d_in[5];
    const float* bv   = (const float*)d_in[6];
    const float* wf   = (const float*)d_in[7];
    const float* bfp  = (const float*)d_in[8];
    const float* ln2g = (const float*)d_in[9];
    const float* ln2b = (const float*)d_in[10];
    const float* w1   = (const float*)d_in[11];
    const float* b1   = (const float*)d_in[12];
    const float* w2   = (const float*)d_in[13];
    const float* b2   = (const float*)d_in[14];
    float* out = (float*)d_out;
    char* ws = (char*)d_ws;

    // workspace layout (total ~148.4 MB)
    unsigned short* whb = (unsigned short*)(ws + 0);
    unsigned short* wvb = (unsigned short*)(ws + 98304);
    unsigned short* wfb = (unsigned short*)(ws + 196608);
    unsigned short* w1b = (unsigned short*)(ws + 327680);
    unsigned short* w2b = (unsigned short*)(ws + 851968);
    const size_t off = 1572864;
    unsigned short* tnb  = (unsigned short*)(ws + off);                    // 21.0 MB
    unsigned short* xt   = (unsigned short*)(ws + off + 20971520ull);      // 21.0 MB
    unsigned short* qkvh = (unsigned short*)(ws + off + 41943040ull);      // 31.5 MB (hid part 1)
    unsigned short* qkvv = (unsigned short*)(ws + off + 73400320ull);      // 31.5 MB (hid part 2)
    unsigned short* ao   = (unsigned short*)(ws + off + 104857600ull);     // 21.0 MB (hid part 3)
    unsigned short* yb   = (unsigned short*)(ws + off + 125829120ull);     // 21.0 MB
    unsigned short* hid  = qkvh;   // hid (N x 1024, 84 MB) overlays qkvh/qkvv/ao (dead by FFN1)

    cvt_all_kernel<<<2688, 256, 0, stream>>>(wh, wv, wf, w1, w2, whb, wvb, wfb, w1b, w2b);

    // fused LN1 + QKV (both halves): writes xt, qkvh, qkvv
    ln1qkv_kernel<<<640, 256, 0, stream>>>(x, ln1g, ln1b, whb, bh, wvb, bv, xt, qkvh, qkvv);

    attn_kernel<<<2048, 256, 0, stream>>>(qkvh, qkvv, ao);

    // proj + residual + LN2 (fused): yb = ao@wf^T + bf + x ; tnb = LN2(yb)
    gemm256_kernel<<<dim3(1, 320), 256, 0, stream>>>(ao, 256, wfb, bfp, yb, 256, xt, nullptr,
                                                     256, 4, ln2g, ln2b, tnb);

    // FFN1: hid = gelu(tn @ w1^T + b1)
    gemm256_kernel<<<dim3(4, 320), 256, 0, stream>>>(tnb, 256, w1b, b1, hid, 1024, nullptr, nullptr,
                                                     256, 2, nullptr, nullptr, nullptr);
    // FFN2 + residual + transpose: out = (y + hid @ w2^T + b2) -> (B,F,C,H,W) fp32
    gemm256_kernel<<<dim3(1, 320), 256, 0, stream>>>(hid, 1024, w2b, b2, nullptr, 256, yb, out,
                                                     1024, 3, nullptr, nullptr, nullptr);
}